// Round 6
// baseline (1017.884 us; speedup 1.0000x reference)
//
#include <hip/hip_runtime.h>
#include <cstdint>
#include <cstddef>

// Problem constants (fixed by reference: B=4, T=2048, D=1024, H=16, DH=64, K=4)
#define TSEQ 2048
#define NB   4
#define NH   16
#define MM   (NB * TSEQ)     // 8192 rows
#define KK   1024            // inner dim for all big GEMMs
#define NCAT 4224            // 1024*4 (q,k,v,g) + 16 (a) + 16 (b) + 96 pad -> 33 tiles of 128

typedef __attribute__((ext_vector_type(8))) __bf16 bf16x8;
typedef __attribute__((ext_vector_type(4))) float f32x4;
typedef __attribute__((ext_vector_type(4))) int   int4v;
typedef __attribute__((ext_vector_type(2))) int   int2v;

__device__ __forceinline__ unsigned short f2bf(float f) {
  unsigned int u = __float_as_uint(f);
  u += 0x7fffu + ((u >> 16) & 1u);          // round-to-nearest-even
  return (unsigned short)(u >> 16);
}
__device__ __forceinline__ float bf2f(unsigned short h) {
  return __uint_as_float(((unsigned int)h) << 16);
}
__device__ __forceinline__ float sigmoidf_(float x) { return 1.0f / (1.0f + expf(-x)); }
__device__ __forceinline__ float siluf_(float x)    { return x / (1.0f + expf(-x)); }

__device__ __forceinline__ uint32_t packsplit(float x) {
  unsigned short h = f2bf(x);
  unsigned short l = f2bf(x - bf2f(h));
  return ((uint32_t)h << 16) | (uint32_t)l;
}

union BF8 { bf16x8 v; unsigned short s[8]; };

// hi/lo fragments from 8 packed u32 with only 8B alignment guaranteed (stride-66 rows)
__device__ __forceinline__ void frag_from_packed8(const uint32_t* p, bf16x8& hi, bf16x8& lo) {
  int2v a = *(const int2v*)p;
  int2v b = *(const int2v*)(p + 2);
  int2v c = *(const int2v*)(p + 4);
  int2v d = *(const int2v*)(p + 6);
  uint32_t uu[8];
  uu[0] = ((const uint32_t*)&a)[0]; uu[1] = ((const uint32_t*)&a)[1];
  uu[2] = ((const uint32_t*)&b)[0]; uu[3] = ((const uint32_t*)&b)[1];
  uu[4] = ((const uint32_t*)&c)[0]; uu[5] = ((const uint32_t*)&c)[1];
  uu[6] = ((const uint32_t*)&d)[0]; uu[7] = ((const uint32_t*)&d)[1];
  BF8 H, L;
#pragma unroll
  for (int e = 0; e < 8; ++e) {
    H.s[e] = (unsigned short)(uu[e] >> 16);
    L.s[e] = (unsigned short)(uu[e] & 0xffffu);
  }
  hi = H.v; lo = L.v;
}

__device__ __forceinline__ f32x4 mfma3(bf16x8 ah, bf16x8 al, bf16x8 bh, bf16x8 bl, f32x4 acc) {
  acc = __builtin_amdgcn_mfma_f32_16x16x32_bf16(ah, bh, acc, 0, 0, 0);
  acc = __builtin_amdgcn_mfma_f32_16x16x32_bf16(ah, bl, acc, 0, 0, 0);
  acc = __builtin_amdgcn_mfma_f32_16x16x32_bf16(al, bh, acc, 0, 0, 0);
  return acc;
}

// async global->LDS, 16B per lane; LDS dest = wave-uniform base + lane*16
#define GLDS16(gp, lp) __builtin_amdgcn_global_load_lds( \
    (const __attribute__((address_space(1))) unsigned int*)(gp), \
    (__attribute__((address_space(3))) unsigned int*)(lp), 16, 0, 0)

// ---------------- split fp32 -> bf16 hi/lo ----------------
__global__ void k_split(const float* __restrict__ x, unsigned short* __restrict__ hi,
                        unsigned short* __restrict__ lo, int n) {
  int idx = blockIdx.x * blockDim.x + threadIdx.x;
  if (idx >= n) return;
  float v = x[idx];
  unsigned short h = f2bf(v);
  hi[idx] = h;
  lo[idx] = f2bf(v - bf2f(h));
}

// ---------------- build Wcat hi/lo ----------------
__global__ void k_build_wcat(const float* __restrict__ Wq, const float* __restrict__ Wk,
                             const float* __restrict__ Wv, const float* __restrict__ Wg,
                             const float* __restrict__ Wa, const float* __restrict__ Wb,
                             unsigned short* __restrict__ hi, unsigned short* __restrict__ lo) {
  int idx = blockIdx.x * blockDim.x + threadIdx.x;
  if (idx >= NCAT * KK) return;
  int row = idx >> 10, col = idx & 1023;
  float v = 0.0f;
  if      (row < 1024) v = Wq[idx];
  else if (row < 2048) v = Wk[idx - 1024 * 1024];
  else if (row < 3072) v = Wv[idx - 2048 * 1024];
  else if (row < 4096) v = Wg[idx - 3072 * 1024];
  else if (row < 4112) v = Wa[(row - 4096) * 1024 + col];
  else if (row < 4128) v = Wb[(row - 4112) * 1024 + col];
  unsigned short h = f2bf(v);
  hi[idx] = h;
  lo[idx] = f2bf(v - bf2f(h));
}

// ---------------- split-bf16 MFMA GEMM, now with global_load_lds staging ----------------
__global__ __launch_bounds__(256, 2)
void k_gemm(const unsigned short* __restrict__ Ahi, const unsigned short* __restrict__ Alo,
            const unsigned short* __restrict__ Bhi, const unsigned short* __restrict__ Blo,
            int Kdim, int mode,
            float* __restrict__ Qb, float* __restrict__ Kb, float* __restrict__ Vb,
            float* __restrict__ Gb, float* __restrict__ Ab, float* __restrict__ Bbuf,
            const float* __restrict__ bg, const float* __restrict__ ba, const float* __restrict__ bb,
            float* __restrict__ Out) {
  __shared__ __align__(16) unsigned short As_hi[128 * 32];
  __shared__ __align__(16) unsigned short As_lo[128 * 32];
  __shared__ __align__(16) unsigned short Bs_hi[128 * 32];
  __shared__ __align__(16) unsigned short Bs_lo[128 * 32];

  const int tid  = threadIdx.x;
  const int lane = tid & 63;
  const int l15  = lane & 15;
  const int quad = lane >> 4;
  const int wid  = tid >> 6;
  const int wm   = (wid >> 1) * 64;
  const int wn   = (wid & 1) * 64;
  const int m0   = blockIdx.x * 128;
  const int n0   = blockIdx.y * 128;
  const int srow = tid >> 2;
  const int skc  = (tid & 3) * 8;

  f32x4 acc[4][4];
  f32x4 zero4 = {0.f, 0.f, 0.f, 0.f};
#pragma unroll
  for (int i = 0; i < 4; ++i)
#pragma unroll
    for (int j = 0; j < 4; ++j) acc[i][j] = zero4;

  // per-lane global source pointers (old byte offset in LDS was exactly tid*16 -> wave base + lane*16)
  const unsigned short* pa0 = Ahi + (size_t)(m0 + srow) * Kdim + skc;
  const unsigned short* pa1 = Ahi + (size_t)(m0 + srow + 64) * Kdim + skc;
  const unsigned short* pa2 = Alo + (size_t)(m0 + srow) * Kdim + skc;
  const unsigned short* pa3 = Alo + (size_t)(m0 + srow + 64) * Kdim + skc;
  const unsigned short* pb0 = Bhi + (size_t)(n0 + srow) * Kdim + skc;
  const unsigned short* pb1 = Bhi + (size_t)(n0 + srow + 64) * Kdim + skc;
  const unsigned short* pb2 = Blo + (size_t)(n0 + srow) * Kdim + skc;
  const unsigned short* pb3 = Blo + (size_t)(n0 + srow + 64) * Kdim + skc;

  char* a0b = (char*)As_hi + wid * 1024;
  char* a1b = (char*)As_hi + 4096 + wid * 1024;
  char* a2b = (char*)As_lo + wid * 1024;
  char* a3b = (char*)As_lo + 4096 + wid * 1024;
  char* b0b = (char*)Bs_hi + wid * 1024;
  char* b1b = (char*)Bs_hi + 4096 + wid * 1024;
  char* b2b = (char*)Bs_lo + wid * 1024;
  char* b3b = (char*)Bs_lo + 4096 + wid * 1024;

  for (int kt = 0; kt < Kdim; kt += 32) {
    __syncthreads();                 // previous tile's LDS reads complete
    GLDS16(pa0 + kt, a0b);
    GLDS16(pa1 + kt, a1b);
    GLDS16(pa2 + kt, a2b);
    GLDS16(pa3 + kt, a3b);
    GLDS16(pb0 + kt, b0b);
    GLDS16(pb1 + kt, b1b);
    GLDS16(pb2 + kt, b2b);
    GLDS16(pb3 + kt, b3b);
    __syncthreads();                 // compiler drains vmcnt before s_barrier -> data visible

    bf16x8 ah[4], al[4], bh[4], bl[4];
#pragma unroll
    for (int f = 0; f < 4; ++f) {
      int ra = (wm + f * 16 + l15) * 32 + quad * 8;
      ah[f] = *(const bf16x8*)&As_hi[ra];
      al[f] = *(const bf16x8*)&As_lo[ra];
      int rb = (wn + f * 16 + l15) * 32 + quad * 8;
      bh[f] = *(const bf16x8*)&Bs_hi[rb];
      bl[f] = *(const bf16x8*)&Bs_lo[rb];
    }
#pragma unroll
    for (int mf = 0; mf < 4; ++mf)
#pragma unroll
      for (int nf = 0; nf < 4; ++nf) {
        acc[mf][nf] = __builtin_amdgcn_mfma_f32_16x16x32_bf16(ah[mf], bh[nf], acc[mf][nf], 0, 0, 0);
        acc[mf][nf] = __builtin_amdgcn_mfma_f32_16x16x32_bf16(ah[mf], bl[nf], acc[mf][nf], 0, 0, 0);
        acc[mf][nf] = __builtin_amdgcn_mfma_f32_16x16x32_bf16(al[mf], bh[nf], acc[mf][nf], 0, 0, 0);
      }
  }

#pragma unroll
  for (int mf = 0; mf < 4; ++mf) {
    int rowb = m0 + wm + mf * 16 + quad * 4;
#pragma unroll
    for (int nf = 0; nf < 4; ++nf) {
      int col = n0 + wn + nf * 16 + l15;
      f32x4 v = acc[mf][nf];
      if (mode == 1) {
#pragma unroll
        for (int r = 0; r < 4; ++r) Out[(size_t)(rowb + r) * 1024 + col] = v[r];
      } else {
        if (col < 1024) {
#pragma unroll
          for (int r = 0; r < 4; ++r) Qb[(size_t)(rowb + r) * 1024 + col] = v[r];
        } else if (col < 2048) {
          int c = col - 1024;
#pragma unroll
          for (int r = 0; r < 4; ++r) Kb[(size_t)(rowb + r) * 1024 + c] = v[r];
        } else if (col < 3072) {
          int c = col - 2048;
#pragma unroll
          for (int r = 0; r < 4; ++r) Vb[(size_t)(rowb + r) * 1024 + c] = v[r];
        } else if (col < 4096) {
          int c = col - 3072;
          float bgc = bg[c];
#pragma unroll
          for (int r = 0; r < 4; ++r) {
            float x = v[r] + bgc;
            Gb[(size_t)(rowb + r) * 1024 + c] = siluf_(x);
          }
        } else if (col < 4112) {
          int c = col - 4096;
          float bac = ba[c];
#pragma unroll
          for (int r = 0; r < 4; ++r) Ab[(size_t)(rowb + r) * 16 + c] = sigmoidf_(v[r] + bac);
        } else if (col < 4128) {
          int c = col - 4112;
          float bbc = bb[c];
#pragma unroll
          for (int r = 0; r < 4; ++r) Bbuf[(size_t)(rowb + r) * 16 + c] = sigmoidf_(v[r] + bbc);
        }
      }
    }
  }
}

// ---------------- k_intra v2: chunk-local WY factors; LDS ~74 KB -> 2 blocks/CU ----------------
// Region multiplexing: K region (Khi|Klo) -> Vp (packed V) -> u0T; Mm -> RTp.
// FS fully in registers (each lane = one RHS column; Mm reads are broadcast).
// KwT bf16-hi only.
__global__ __launch_bounds__(256, 2)
void k_intra(const float* __restrict__ Qb, const float* __restrict__ Kb,
             const float* __restrict__ Vb,
             const float* __restrict__ Ab, const float* __restrict__ Bb,
             const float* __restrict__ cqw, const float* __restrict__ cqb,
             const float* __restrict__ ckw, const float* __restrict__ ckb,
             const float* __restrict__ cvw, const float* __restrict__ cvb,
             uint32_t* __restrict__ A1buf, unsigned short* __restrict__ Qefbuf,
             unsigned short* __restrict__ G1buf, unsigned short* __restrict__ G2Tbuf,
             float* __restrict__ gCbuf) {
  __shared__ __align__(16) unsigned short KK2[2][64][72];  // Khi|Klo; later Vp, then u0T (u32[64][66])
  __shared__ __align__(16) unsigned short QQ2[2][64][72];  // Qhi|Qlo (live through Qeff epilogue)
  __shared__ __align__(16) float Mm[64][68];               // FS matrix; later RTp (u32[64][66])
  __shared__ __align__(16) unsigned short Atthi[64][72];
  __shared__ __align__(16) unsigned short KwThi[64][72];   // bf16-hi only
  __shared__ float lgs[64], gas[64], bss[64], wvs[64], ins[64];

  unsigned short (*Khi)[72] = KK2[0];
  unsigned short (*Klo)[72] = KK2[1];
  unsigned short (*Qhi)[72] = QQ2[0];
  unsigned short (*Qlo)[72] = QQ2[1];
  uint32_t (*Vp)[66]  = (uint32_t (*)[66])&KK2[0][0][0];
  uint32_t (*u0T)[66] = (uint32_t (*)[66])&KK2[0][0][0];
  uint32_t (*RTp)[66] = (uint32_t (*)[66])&Mm[0][0];

  const int tid  = threadIdx.x;
  const int lane = tid & 63;
  const int w    = tid >> 6;
  const int l15  = lane & 15;
  const int quad = lane >> 4;
  const int bid  = blockIdx.x;
  const int c    = bid & 31;
  const int h    = (bid >> 5) & 15;
  const int b    = bid >> 9;
  const size_t ci = (size_t)bid;
  const int t0   = c * 64;
  const long rowBase = (long)b * 2048 + t0;
  const int ch   = h * 64 + lane;
  const f32x4 z4 = {0.f, 0.f, 0.f, 0.f};

  float u[64];       // FS working column (waves 0/1)
  float vvals[16];   // producer V values, held until Vp staging

  // ---- P0: gates (all waves redundant; identical values -> benign LDS write race) ----
  {
    long gr = (rowBase + lane) * 16 + h;
    float av = Ab[gr], bv = Bb[gr];
    float x = log2f(av);
#pragma unroll
    for (int off = 1; off < 64; off <<= 1) {
      float y = __shfl_up(x, off);
      if (lane >= off) x += y;
    }
    float l63 = __shfl(x, 63);
    lgs[lane] = x;
    gas[lane] = exp2f(x);
    bss[lane] = bv;
    wvs[lane] = exp2f(l63 - x) * bv;
  }

  // ---- P1: conv + silu producers; wave w covers s = w*16..w*16+15 ----
  {
    const float kc0 = ckw[ch * 4], kc1 = ckw[ch * 4 + 1], kc2 = ckw[ch * 4 + 2], kc3 = ckw[ch * 4 + 3], kcbv = ckb[ch];
    const float qc0 = cqw[ch * 4], qc1 = cqw[ch * 4 + 1], qc2 = cqw[ch * 4 + 2], qc3 = cqw[ch * 4 + 3], qcbv = cqb[ch];
    const float vc0 = cvw[ch * 4], vc1 = cvw[ch * 4 + 1], vc2 = cvw[ch * 4 + 2], vc3 = cvw[ch * 4 + 3], vcbv = cvb[ch];
    const int tb = t0 + w * 16;
    float kw0, kw1, kw2, qw0, qw1, qw2, vw0, vw1, vw2;
    {
      float kx[3], qx[3], vx[3];
#pragma unroll
      for (int d = 0; d < 3; ++d) {
        int tt = tb - 3 + d;
        float a = 0.f, bq = 0.f, cv = 0.f;
        if (tt >= 0) {
          long ro = ((long)b * 2048 + tt) * 1024 + ch;
          a = Kb[ro]; bq = Qb[ro]; cv = Vb[ro];
        }
        kx[d] = a; qx[d] = bq; vx[d] = cv;
      }
      kw0 = kx[0]; kw1 = kx[1]; kw2 = kx[2];
      qw0 = qx[0]; qw1 = qx[1]; qw2 = qx[2];
      vw0 = vx[0]; vw1 = vx[1]; vw2 = vx[2];
    }
#pragma unroll
    for (int lt = 0; lt < 16; ++lt) {
      const int s = w * 16 + lt;
      const long ro = (rowBase + s) * 1024 + ch;
      float kr = Kb[ro], qr = Qb[ro], vr = Vb[ro];
      float kcv = kcbv + kc0 * kw0 + kc1 * kw1 + kc2 * kw2 + kc3 * kr;
      float qcv = qcbv + qc0 * qw0 + qc1 * qw1 + qc2 * qw2 + qc3 * qr;
      float vcv = vcbv + vc0 * vw0 + vc1 * vw1 + vc2 * vw2 + vc3 * vr;
      kw0 = kw1; kw1 = kw2; kw2 = kr;
      qw0 = qw1; qw1 = qw2; qw2 = qr;
      vw0 = vw1; vw1 = vw2; vw2 = vr;
      float kv = siluf_(kcv), qv = siluf_(qcv);
      vvals[lt] = siluf_(vcv);
      uint32_t kp_ = packsplit(kv);
      uint32_t qp_ = packsplit(qv);
      Khi[s][lane] = (unsigned short)(kp_ >> 16); Klo[s][lane] = (unsigned short)(kp_ & 0xffffu);
      Qhi[s][lane] = (unsigned short)(qp_ >> 16); Qlo[s][lane] = (unsigned short)(qp_ & 0xffffu);
    }
  }
  __syncthreads();                                     // B1

  // ---- P2: accM = K K^T strip, accA = Q K^T strip ----
  f32x4 accM[4], accA[4];
#pragma unroll
  for (int nt = 0; nt < 4; ++nt) { accM[nt] = z4; accA[nt] = z4; }
#pragma unroll
  for (int ks = 0; ks < 2; ++ks) {
    bf16x8 kah = *(const bf16x8*)&Khi[w * 16 + l15][ks * 32 + quad * 8];
    bf16x8 kal = *(const bf16x8*)&Klo[w * 16 + l15][ks * 32 + quad * 8];
    bf16x8 qah = *(const bf16x8*)&Qhi[w * 16 + l15][ks * 32 + quad * 8];
    bf16x8 qal = *(const bf16x8*)&Qlo[w * 16 + l15][ks * 32 + quad * 8];
#pragma unroll
    for (int nt = 0; nt < 4; ++nt) {
      bf16x8 bh = *(const bf16x8*)&Khi[nt * 16 + l15][ks * 32 + quad * 8];
      bf16x8 bl = *(const bf16x8*)&Klo[nt * 16 + l15][ks * 32 + quad * 8];
      accM[nt] = mfma3(kah, kal, bh, bl, accM[nt]);
      accA[nt] = mfma3(qah, qal, bh, bl, accA[nt]);
    }
  }
#pragma unroll
  for (int nt = 0; nt < 4; ++nt)
    if (nt == w) {
#pragma unroll
      for (int r = 0; r < 4; ++r)
        if (l15 == quad * 4 + r) ins[nt * 16 + l15] = rsqrtf(fmaxf(accM[nt][r], 1e-24f));
    }
  __syncthreads();                                     // B2

  // ---- P2-epi: Mm, Atthi (fused exp2f -- gamma spans 2^+-200, split form would inf*0);
  //      KwT build (hi-only); wave1 gathers R-init columns into regs ----
  {
#pragma unroll
    for (int nt = 0; nt < 4; ++nt) {
      int sc = nt * 16 + l15;
      float insc = ins[sc], lgc = lgs[sc], bsc = bss[sc];
#pragma unroll
      for (int r = 0; r < 4; ++r) {
        int sr = w * 16 + quad * 4 + r;
        Mm[sr][sc] = (sc < sr) ? exp2f(lgs[sr] - lgc) * bsc * ins[sr] * insc * accM[nt][r] : 0.f;
        Atthi[sr][sc] = f2bf((sc <= sr) ? exp2f(lgs[sr] - lgc) * bsc * insc * accA[nt][r] : 0.f);
      }
    }
    int s = w * 16 + (lane & 15);
    int jb = (lane >> 4) * 16;
    float wsc = wvs[s] * ins[s];
    BF8 H0, L0, H1, L1;
    H0.v = *(const bf16x8*)&Khi[s][jb];     L0.v = *(const bf16x8*)&Klo[s][jb];
    H1.v = *(const bf16x8*)&Khi[s][jb + 8]; L1.v = *(const bf16x8*)&Klo[s][jb + 8];
#pragma unroll
    for (int e = 0; e < 8; ++e) {
      float kv0 = bf2f(H0.s[e]) + bf2f(L0.s[e]);
      float kv1 = bf2f(H1.s[e]) + bf2f(L1.s[e]);
      KwThi[jb + e][s]     = f2bf(kv0 * wsc);
      KwThi[jb + 8 + e][s] = f2bf(kv1 * wsc);
    }
    if (w == 1) {      // R-init[s][lane] = gas[s]*ins[s]*k[s][lane] (lane = column)
#pragma unroll
      for (int s2 = 0; s2 < 64; ++s2) {
        float kv = bf2f(Khi[s2][lane]) + bf2f(Klo[s2][lane]);
        u[s2] = gas[s2] * ins[s2] * kv;
      }
    }
  }
  if (tid == 0) gCbuf[ci] = gas[63];
  __syncthreads();                                     // B3 (K region dead)

  // ---- stage V packed into K region ----
#pragma unroll
  for (int lt = 0; lt < 16; ++lt) Vp[w * 16 + lt][lane] = packsplit(vvals[lt]);
  __syncthreads();                                     // B4

  // ---- FS in registers: wave0 solves (I+M)u0 = V, wave1 solves (I+M)R = R-init ----
  if (w == 0) {
#pragma unroll
    for (int s2 = 0; s2 < 64; ++s2) {
      uint32_t p = Vp[s2][lane];
      u[s2] = bf2f((unsigned short)(p >> 16)) + bf2f((unsigned short)(p & 0xffffu));
    }
  }
  if (w < 2) {
#pragma unroll
    for (int d = 0; d < 4; ++d) {
      const int base = d * 16;
#pragma unroll
      for (int r2 = 1; r2 < 16; ++r2) {
        float acc = u[base + r2];
#pragma unroll
        for (int r = 0; r < r2; ++r) acc = fmaf(-Mm[base + r2][base + r], u[base + r], acc);
        u[base + r2] = acc;
      }
      if (d < 3) {
#pragma unroll
        for (int s2 = base + 16; s2 < 64; ++s2) {
          f32x4 m0 = *(const f32x4*)&Mm[s2][base];
          f32x4 m1 = *(const f32x4*)&Mm[s2][base + 4];
          f32x4 m2 = *(const f32x4*)&Mm[s2][base + 8];
          f32x4 m3 = *(const f32x4*)&Mm[s2][base + 12];
          float a0 = m0[0] * u[base + 0] + m0[1] * u[base + 1] + m0[2] * u[base + 2] + m0[3] * u[base + 3];
          float a1 = m1[0] * u[base + 4] + m1[1] * u[base + 5] + m1[2] * u[base + 6] + m1[3] * u[base + 7];
          float a2 = m2[0] * u[base + 8] + m2[1] * u[base + 9] + m2[2] * u[base + 10] + m2[3] * u[base + 11];
          float a3 = m3[0] * u[base + 12] + m3[1] * u[base + 13] + m3[2] * u[base + 14] + m3[3] * u[base + 15];
          u[s2] = u[s2] - ((a0 + a1) + (a2 + a3));
        }
      }
    }
  }
  __syncthreads();                                     // B5 (Mm + Vp reads done)

  // wave0 lane i holds u0 column i == u0T row i; wave1 lane j holds R column j == RTp row j
  if (w == 0) {
#pragma unroll
    for (int s2 = 0; s2 < 64; ++s2) u0T[lane][s2] = packsplit(u[s2]);
  } else if (w == 1) {
#pragma unroll
    for (int s2 = 0; s2 < 64; ++s2) RTp[lane][s2] = packsplit(u[s2]);
  }
  __syncthreads();                                     // B6

  // ---- P6: output GEMMs ----
  // A1 = Att * u0
  {
    f32x4 acc[4];
#pragma unroll
    for (int nt = 0; nt < 4; ++nt) acc[nt] = z4;
#pragma unroll
    for (int ks = 0; ks < 2; ++ks) {
      bf16x8 ta = *(const bf16x8*)&Atthi[w * 16 + l15][ks * 32 + quad * 8];
#pragma unroll
      for (int nt = 0; nt < 4; ++nt) {
        bf16x8 uh, ul;
        frag_from_packed8(&u0T[nt * 16 + l15][ks * 32 + quad * 8], uh, ul);
        acc[nt] = __builtin_amdgcn_mfma_f32_16x16x32_bf16(ta, uh, acc[nt], 0, 0, 0);
        acc[nt] = __builtin_amdgcn_mfma_f32_16x16x32_bf16(ta, ul, acc[nt], 0, 0, 0);
      }
    }
#pragma unroll
    for (int nt = 0; nt < 4; ++nt)
#pragma unroll
      for (int r = 0; r < 4; ++r) {
        int t = w * 16 + quad * 4 + r, i = nt * 16 + l15;
        A1buf[ci * 4096 + t * 64 + i] = packsplit(acc[nt][r]);
      }
  }
  // Qeff = gamma*Q - Att*R
  {
    f32x4 acc[4];
#pragma unroll
    for (int nt = 0; nt < 4; ++nt) acc[nt] = z4;
#pragma unroll
    for (int ks = 0; ks < 2; ++ks) {
      bf16x8 ta = *(const bf16x8*)&Atthi[w * 16 + l15][ks * 32 + quad * 8];
#pragma unroll
      for (int nt = 0; nt < 4; ++nt) {
        bf16x8 rh, rl;
        frag_from_packed8(&RTp[nt * 16 + l15][ks * 32 + quad * 8], rh, rl);
        acc[nt] = __builtin_amdgcn_mfma_f32_16x16x32_bf16(ta, rh, acc[nt], 0, 0, 0);
        acc[nt] = __builtin_amdgcn_mfma_f32_16x16x32_bf16(ta, rl, acc[nt], 0, 0, 0);
      }
    }
#pragma unroll
    for (int nt = 0; nt < 4; ++nt)
#pragma unroll
      for (int r = 0; r < 4; ++r) {
        int t = w * 16 + quad * 4 + r, j = nt * 16 + l15;
        float q = bf2f(Qhi[t][j]) + bf2f(Qlo[t][j]);
        Qefbuf[ci * 4096 + t * 64 + j] = f2bf(gas[t] * q - acc[nt][r]);
      }
  }
  // G1 = u0T x KwT (KwT hi-only)
  {
    f32x4 acc[4];
#pragma unroll
    for (int nt = 0; nt < 4; ++nt) acc[nt] = z4;
#pragma unroll
    for (int ks = 0; ks < 2; ++ks) {
      bf16x8 uh, ul;
      frag_from_packed8(&u0T[w * 16 + l15][ks * 32 + quad * 8], uh, ul);
#pragma unroll
      for (int nt = 0; nt < 4; ++nt) {
        bf16x8 kh = *(const bf16x8*)&KwThi[nt * 16 + l15][ks * 32 + quad * 8];
        acc[nt] = __builtin_amdgcn_mfma_f32_16x16x32_bf16(uh, kh, acc[nt], 0, 0, 0);
        acc[nt] = __builtin_amdgcn_mfma_f32_16x16x32_bf16(ul, kh, acc[nt], 0, 0, 0);
      }
    }
#pragma unroll
    for (int nt = 0; nt < 4; ++nt)
#pragma unroll
      for (int r = 0; r < 4; ++r) {
        int i = w * 16 + quad * 4 + r, j = nt * 16 + l15;
        G1buf[ci * 4096 + i * 64 + j] = f2bf(acc[nt][r]);
      }
  }
  // G2T: G2[m][j] = RTp x KwT ; stored transposed [j][m]
  {
    f32x4 acc[4];
#pragma unroll
    for (int nt = 0; nt < 4; ++nt) acc[nt] = z4;
#pragma unroll
    for (int ks = 0; ks < 2; ++ks) {
      bf16x8 rh, rl;
      frag_from_packed8(&RTp[w * 16 + l15][ks * 32 + quad * 8], rh, rl);
#pragma unroll
      for (int nt = 0; nt < 4; ++nt) {
        bf16x8 kh = *(const bf16x8*)&KwThi[nt * 16 + l15][ks * 32 + quad * 8];
        acc[nt] = __builtin_amdgcn_mfma_f32_16x16x32_bf16(rh, kh, acc[nt], 0, 0, 0);
        acc[nt] = __builtin_amdgcn_mfma_f32_16x16x32_bf16(rl, kh, acc[nt], 0, 0, 0);
      }
    }
#pragma unroll
    for (int nt = 0; nt < 4; ++nt) {
      int j = nt * 16 + l15;
      int mb = w * 16 + quad * 4;
      uint32_t lo32 = (uint32_t)f2bf(acc[nt][0]) | ((uint32_t)f2bf(acc[nt][1]) << 16);
      uint32_t hi32 = (uint32_t)f2bf(acc[nt][2]) | ((uint32_t)f2bf(acc[nt][3]) << 16);
      uint32_t* dst = (uint32_t*)&G2Tbuf[ci * 4096 + j * 64 + mb];
      dst[0] = lo32; dst[1] = hi32;
    }
  }
}

// ---------------- k_serial: 32-step state recurrence on precomputed factors (unchanged) ----------------
__global__ __launch_bounds__(256)
void k_serial(const uint32_t* __restrict__ A1buf, const unsigned short* __restrict__ Qefbuf,
              const unsigned short* __restrict__ G1buf, const unsigned short* __restrict__ G2Tbuf,
              const float* __restrict__ gCbuf, const float* __restrict__ Gb,
              unsigned short* __restrict__ Yhi, unsigned short* __restrict__ Ylo) {
  __shared__ uint32_t A1L[64][66];
  __shared__ __align__(16) unsigned short QefL[64][72], G1L[64][72], G2TL[64][72];
  __shared__ __align__(16) unsigned short S0hi[64][72], S0lo[64][72];
  __shared__ float S0f[64][65];

  const int tid  = threadIdx.x;
  const int lane = tid & 63;
  const int w    = tid >> 6;
  const int l15  = lane & 15;
  const int quad = lane >> 4;
  const int b    = blockIdx.x >> 4;
  const int h    = blockIdx.x & 15;
  const size_t bh = (size_t)blockIdx.x;
  const f32x4 z4 = {0.f, 0.f, 0.f, 0.f};

  for (int n = tid; n < 64 * 65; n += 256) (&S0f[0][0])[n] = 0.f;
  for (int n = tid; n < 64 * 72; n += 256) { (&S0hi[0][0])[n] = 0; (&S0lo[0][0])[n] = 0; }

  uint32_t rA[16], rQ[8], rG1[8], rG2[8];
  float pg[16], pgC;
  {
    const uint32_t* pA = A1buf + bh * 32 * 4096;
    const uint32_t* pQ = (const uint32_t*)Qefbuf + bh * 32 * 2048;
    const uint32_t* pG1 = (const uint32_t*)G1buf + bh * 32 * 2048;
    const uint32_t* pG2 = (const uint32_t*)G2Tbuf + bh * 32 * 2048;
#pragma unroll
    for (int k = 0; k < 16; ++k) rA[k] = pA[tid + k * 256];
#pragma unroll
    for (int k = 0; k < 8; ++k) { rQ[k] = pQ[tid + k * 256]; rG1[k] = pG1[tid + k * 256]; rG2[k] = pG2[tid + k * 256]; }
    pgC = gCbuf[bh * 32];
#pragma unroll
    for (int nt = 0; nt < 4; ++nt)
#pragma unroll
      for (int r = 0; r < 4; ++r)
        pg[nt * 4 + r] = Gb[((long)b * 2048 + w * 16 + quad * 4 + r) * 1024 + h * 64 + nt * 16 + l15];
  }
  __syncthreads();

#pragma unroll 1
  for (int c = 0; c < 32; ++c) {
#pragma unroll
    for (int k = 0; k < 16; ++k) {
      int idx = tid + k * 256;
      A1L[idx >> 6][idx & 63] = rA[k];
    }
#pragma unroll
    for (int k = 0; k < 8; ++k) {
      int i32 = tid + k * 256;
      int row = i32 >> 5, col = (i32 & 31) * 2;
      *(uint32_t*)&QefL[row][col] = rQ[k];
      *(uint32_t*)&G1L[row][col]  = rG1[k];
      *(uint32_t*)&G2TL[row][col] = rG2[k];
    }
    float gC = pgC;
    float pgl[16];
#pragma unroll
    for (int e = 0; e < 16; ++e) pgl[e] = pg[e];
    __syncthreads();                                   // B1

    f32x4 accO[4], accS[4];
#pragma unroll
    for (int nt = 0; nt < 4; ++nt) { accO[nt] = z4; accS[nt] = z4; }
#pragma unroll
    for (int ks = 0; ks < 2; ++ks) {
      bf16x8 qa = *(const bf16x8*)&QefL[w * 16 + l15][ks * 32 + quad * 8];
      bf16x8 sah = *(const bf16x8*)&S0hi[w * 16 + l15][ks * 32 + quad * 8];
      bf16x8 sal = *(const bf16x8*)&S0lo[w * 16 + l15][ks * 32 + quad * 8];
#pragma unroll
      for (int nt = 0; nt < 4; ++nt) {
        bf16x8 sh = *(const bf16x8*)&S0hi[nt * 16 + l15][ks * 32 + quad * 8];
        bf16x8 sl = *(const bf16x8*)&S0lo[nt * 16 + l15][ks * 32 + quad * 8];
        accO[nt] = __builtin_amdgcn_mfma_f32_16x16x32_bf16(qa, sh, accO[nt], 0, 0, 0);
        accO[nt] = __builtin_amdgcn_mfma_f32_16x16x32_bf16(qa, sl, accO[nt], 0, 0, 0);
        bf16x8 g2 = *(const bf16x8*)&G2TL[nt * 16 + l15][ks * 32 + quad * 8];
        accS[nt] = __builtin_amdgcn_mfma_f32_16x16x32_bf16(sah, g2, accS[nt], 0, 0, 0);
        accS[nt] = __builtin_amdgcn_mfma_f32_16x16x32_bf16(sal, g2, accS[nt], 0, 0, 0);
      }
    }
    {
      const int cc = (c + 1 < 32) ? c + 1 : 31;
      const uint32_t* pA = A1buf + (bh * 32 + cc) * 4096;
      const uint32_t* pQ = (const uint32_t*)Qefbuf + (bh * 32 + cc) * 2048;
      const uint32_t* pG1 = (const uint32_t*)G1buf + (bh * 32 + cc) * 2048;
      const uint32_t* pG2 = (const uint32_t*)G2Tbuf + (bh * 32 + cc) * 2048;
#pragma unroll
      for (int k = 0; k < 16; ++k) rA[k] = pA[tid + k * 256];
#pragma unroll
      for (int k = 0; k < 8; ++k) { rQ[k] = pQ[tid + k * 256]; rG1[k] = pG1[tid + k * 256]; rG2[k] = pG2[tid + k * 256]; }
      pgC = gCbuf[bh * 32 + cc];
#pragma unroll
      for (int nt = 0; nt < 4; ++nt)
#pragma unroll
        for (int r = 0; r < 4; ++r)
          pg[nt * 4 + r] = Gb[((long)b * 2048 + cc * 64 + w * 16 + quad * 4 + r) * 1024 + h * 64 + nt * 16 + l15];
    }
    __syncthreads();                                   // B2

#pragma unroll
    for (int nt = 0; nt < 4; ++nt)
#pragma unroll
      for (int r = 0; r < 4; ++r) {
        int t = w * 16 + quad * 4 + r, i = nt * 16 + l15;
        uint32_t a1 = A1L[t][i];
        float o = accO[nt][r] + bf2f((unsigned short)(a1 >> 16)) + bf2f((unsigned short)(a1 & 0xffffu));
        float y = o * pgl[nt * 4 + r];
        long ro = ((long)b * 2048 + c * 64 + t) * 1024 + h * 64 + i;
        unsigned short hy = f2bf(y);
        Yhi[ro] = hy;
        Ylo[ro] = f2bf(y - bf2f(hy));
      }
#pragma unroll
    for (int nt = 0; nt < 4; ++nt)
#pragma unroll
      for (int r = 0; r < 4; ++r) {
        int i = w * 16 + quad * 4 + r, j = nt * 16 + l15;
        float sn = gC * S0f[i][j] + bf2f(G1L[i][j]) - accS[nt][r];
        S0f[i][j] = sn;
        uint32_t p = packsplit(sn);
        S0hi[i][j] = (unsigned short)(p >> 16);
        S0lo[i][j] = (unsigned short)(p & 0xffffu);
      }
    __syncthreads();                                   // B3
  }
}

extern "C" void kernel_launch(void* const* d_in, const int* in_sizes, int n_in,
                              void* d_out, int out_size, void* d_ws, size_t ws_size,
                              hipStream_t stream) {
  const float* X   = (const float*)d_in[0];
  const float* Wq  = (const float*)d_in[1];
  const float* Wk  = (const float*)d_in[2];
  const float* Wv  = (const float*)d_in[3];
  const float* Wa  = (const float*)d_in[4];
  const float* ba  = (const float*)d_in[5];
  const float* Wb  = (const float*)d_in[6];
  const float* bb  = (const float*)d_in[7];
  const float* cqw = (const float*)d_in[8];
  const float* cqb = (const float*)d_in[9];
  const float* ckw = (const float*)d_in[10];
  const float* ckb = (const float*)d_in[11];
  const float* cvw = (const float*)d_in[12];
  const float* cvb = (const float*)d_in[13];
  const float* Wg  = (const float*)d_in[14];
  const float* bg  = (const float*)d_in[15];
  const float* Wo  = (const float*)d_in[16];
  float* Out = (float*)d_out;

  char* ws = (char*)d_ws;
  size_t off = 0;
  auto alloc = [&](size_t bytes) -> void* {
    void* p = ws + off;
    off += (bytes + 255) & ~(size_t)255;
    return p;
  };
  // base ~152.6 MB + intra factors 67.1 MB = ~219.8 MB peak
  unsigned short* Xhi = (unsigned short*)alloc((size_t)MM * KK * 2);
  unsigned short* Xlo = (unsigned short*)alloc((size_t)MM * KK * 2);
  unsigned short* Whi = (unsigned short*)alloc((size_t)NCAT * KK * 2);
  unsigned short* Wlo = (unsigned short*)alloc((size_t)NCAT * KK * 2);
  float* Qb  = (float*)alloc((size_t)MM * 1024 * 4);
  float* Kb  = (float*)alloc((size_t)MM * 1024 * 4);
  float* Vb  = (float*)alloc((size_t)MM * 1024 * 4);
  float* Ab  = (float*)alloc((size_t)MM * 16 * 4);
  float* Bbf = (float*)alloc((size_t)MM * 16 * 4);
  uint32_t*       A1buf  = (uint32_t*)alloc((size_t)2048 * 4096 * 4);
  unsigned short* G1buf  = (unsigned short*)alloc((size_t)2048 * 4096 * 2);
  unsigned short* G2Tbuf = (unsigned short*)alloc((size_t)2048 * 4096 * 2);
  float*          gCbuf  = (float*)alloc((size_t)2048 * 4);
  // aliases of dead regions
  float* Gb = Out;
  unsigned short* Yhi = Xhi;
  unsigned short* Ylo = Xlo;
  unsigned short* Qefbuf = Whi;
  unsigned short* Wohi = Whi;
  unsigned short* Wolo = Wlo;

  const int nX = MM * KK;
  k_split<<<(nX + 255) / 256, 256, 0, stream>>>(X, Xhi, Xlo, nX);
  k_build_wcat<<<(NCAT * KK + 255) / 256, 256, 0, stream>>>(Wq, Wk, Wv, Wg, Wa, Wb, Whi, Wlo);
  k_gemm<<<dim3(MM / 128, NCAT / 128), 256, 0, stream>>>(
      Xhi, Xlo, Whi, Wlo, KK, 0, Qb, Kb, Vb, Gb, Ab, Bbf, bg, ba, bb, nullptr);
  k_intra<<<NB * NH * 32, 256, 0, stream>>>(Qb, Kb, Vb, Ab, Bbf,
                                            cqw, cqb, ckw, ckb, cvw, cvb,
                                            A1buf, Qefbuf, G1buf, G2Tbuf, gCbuf);
  k_serial<<<NB * NH, 256, 0, stream>>>(A1buf, Qefbuf, G1buf, G2Tbuf, gCbuf, Gb, Yhi, Ylo);
  k_split<<<(1024 * 1024 + 255) / 256, 256, 0, stream>>>(Wo, Wohi, Wolo, 1024 * 1024);
  k_gemm<<<dim3(MM / 128, 1024 / 128), 256, 0, stream>>>(
      Yhi, Ylo, Wohi, Wolo, KK, 1, nullptr, nullptr, nullptr, nullptr, nullptr, nullptr,
      nullptr, nullptr, nullptr, Out);
}